// Round 1
// baseline (1477.702 us; speedup 1.0000x reference)
//
#include <hip/hip_runtime.h>
#include <math.h>

#define HID    128
#define NTREE  6000
#define NGRAPH 144000
#define NNODE  150000
#define NEDGE  600000
#define NSEG   4096
#define AF     34
#define EPSF   1e-8f

#define SCAN_BLK   256
#define SCAN_ELEMS 1024
#define NSCAN ((NNODE + SCAN_ELEMS - 1) / SCAN_ELEMS)   // 147

// ---------------- reductions ----------------

__device__ __forceinline__ float waveReduceSum(float v) {
#pragma unroll
  for (int o = 32; o > 0; o >>= 1) v += __shfl_down(v, o, 64);
  return v;
}

// block of exactly 128 threads (2 waves)
__device__ __forceinline__ float blockReduce128(float v, float* red) {
  v = waveReduceSum(v);
  int w = threadIdx.x >> 6;
  if ((threadIdx.x & 63) == 0) red[w] = v;
  __syncthreads();
  float r = red[0] + red[1];
  __syncthreads();
  return r;
}

// block of 256 threads = 2 independent groups of 128; reduce within group
__device__ __forceinline__ float grpReduce128(float v, float (*red)[2]) {
  v = waveReduceSum(v);
  int G = threadIdx.x >> 7;
  int w = (threadIdx.x >> 6) & 1;
  if ((threadIdx.x & 63) == 0) red[G][w] = v;
  __syncthreads();
  float r = red[G][0] + red[G][1];
  __syncthreads();
  return r;
}

// ---------------- CSR build ----------------

__global__ void k_hist(const int* __restrict__ dst, int* __restrict__ deg) {
  int e = blockIdx.x * blockDim.x + threadIdx.x;
  if (e < NEDGE) atomicAdd(&deg[dst[e]], 1);
}

__global__ void k_scan1(const int* __restrict__ deg, int* __restrict__ off,
                        int* __restrict__ part) {
  __shared__ int s[SCAN_BLK];
  int b = blockIdx.x, t = threadIdx.x;
  int base = b * SCAN_ELEMS + t * 4;
  int v0 = 0, v1 = 0, v2 = 0, v3 = 0;
  if (base + 0 < NNODE) v0 = deg[base + 0];
  if (base + 1 < NNODE) v1 = deg[base + 1];
  if (base + 2 < NNODE) v2 = deg[base + 2];
  if (base + 3 < NNODE) v3 = deg[base + 3];
  int sum = v0 + v1 + v2 + v3;
  s[t] = sum;
  __syncthreads();
  for (int o = 1; o < SCAN_BLK; o <<= 1) {
    int x = (t >= o) ? s[t - o] : 0;
    __syncthreads();
    s[t] += x;
    __syncthreads();
  }
  int run = s[t] - sum;  // exclusive prefix for this thread within block
  run += v0; if (base + 0 < NNODE) off[base + 1] = run;
  run += v1; if (base + 1 < NNODE) off[base + 2] = run;
  run += v2; if (base + 2 < NNODE) off[base + 3] = run;
  run += v3; if (base + 3 < NNODE) off[base + 4] = run;
  if (t == SCAN_BLK - 1) part[b] = s[t];
  if (b == 0 && t == 0) off[0] = 0;
}

__global__ void k_scan2(int* part, int nb) {
  __shared__ int s[SCAN_BLK];
  int t = threadIdx.x;
  s[t] = (t < nb) ? part[t] : 0;
  __syncthreads();
  for (int o = 1; o < SCAN_BLK; o <<= 1) {
    int x = (t >= o) ? s[t - o] : 0;
    __syncthreads();
    s[t] += x;
    __syncthreads();
  }
  if (t < nb) part[t] = s[t];
}

__global__ void k_scan3(int* __restrict__ off, const int* __restrict__ part) {
  int b = blockIdx.x;
  if (b == 0) return;
  int add = part[b - 1];
  int base = b * SCAN_ELEMS + threadIdx.x * 4 + 1;
#pragma unroll
  for (int j = 0; j < 4; j++) {
    int idx = base + j;
    if (idx <= NNODE) off[idx] += add;
  }
}

__global__ void k_fill(const int* __restrict__ dst, const int* __restrict__ src,
                       const float* __restrict__ ew, int* __restrict__ cur,
                       int* __restrict__ sperm, float* __restrict__ wperm) {
  int e = blockIdx.x * blockDim.x + threadIdx.x;
  if (e < NEDGE) {
    int d = dst[e];
    int p = atomicAdd(&cur[d], 1);
    sperm[p] = src[e];
    wperm[p] = ew[e];
  }
}

// ---------------- embedding (expmap0 + lorentz_linear W0) ----------------

__global__ void k_embed(const float* __restrict__ gfeat, const float* __restrict__ tfeat,
                        const float* __restrict__ W0, const float* __restrict__ b0,
                        const float* __restrict__ scale0, float* __restrict__ xout) {
  int row = blockIdx.x;
  int t = threadIdx.x;
  if (row < NTREE) {
    xout[row * HID + t] = tfeat[row * HID + t];
    return;
  }
  int g = row - NTREE;
  __shared__ float sp[AF];
  __shared__ float gfe[AF + 1];
  __shared__ float red[2];
  __shared__ float y0s;
  if (t < AF) sp[t] = gfeat[g * AF + t];
  __syncthreads();
  float ss = 0.f;
#pragma unroll
  for (int k = 0; k < AF; k++) { float x = sp[k]; ss += x * x; }
  float nrm = fmaxf(sqrtf(ss), EPSF);
  if (t == 0) gfe[0] = coshf(nrm);
  if (t < AF) gfe[t + 1] = sinhf(nrm) / nrm * sp[t];
  __syncthreads();
  float acc = b0[t];
  const float* wr = W0 + t * (AF + 1);
#pragma unroll
  for (int k = 0; k < AF + 1; k++) acc += wr[k] * gfe[k];
  if (t == 0) y0s = acc;
  __syncthreads();
  float escale = expf(scale0[0]);
  float timec = 1.f / (1.f + expf(-y0s)) * escale + 1.1f;
  float part = (t == 0) ? 0.f : acc * acc;
  float ssum = blockReduce128(part, red);
  float s = (timec * timec - 1.f) / fmaxf(ssum, EPSF);
  float sq = sqrtf(s);
  xout[row * HID + t] = (t == 0) ? timec : acc * sq;
}

// ---------------- lorentz_linear (128x128) ----------------
// 256 threads = 2 groups of 128; each group computes 4 rows; thread t = output dim.

template <int RELU>
__global__ void k_linear(const float* __restrict__ in, const float* __restrict__ W,
                         const float* __restrict__ b, const float* __restrict__ scale,
                         float* __restrict__ out) {
  __shared__ __align__(16) float xs[2][4][HID];
  __shared__ float red[2][2];
  __shared__ float y0s[2][4];
  const int G = threadIdx.x >> 7;
  const int t = threadIdx.x & 127;
  const int row0 = (blockIdx.x * 2 + G) * 4;
#pragma unroll
  for (int r = 0; r < 4; r++) {
    int row = row0 + r;
    float v = (row < NNODE) ? in[row * HID + t] : 0.f;
    if (RELU) v = fmaxf(v, 0.f);
    xs[G][r][t] = v;
  }
  __syncthreads();
  float acc[4];
  float bb = b[t];
#pragma unroll
  for (int r = 0; r < 4; r++) acc[r] = bb;
  const float4* Wv = (const float4*)(W + t * HID);
#pragma unroll 8
  for (int k4 = 0; k4 < HID / 4; k4++) {
    float4 w = Wv[k4];
#pragma unroll
    for (int r = 0; r < 4; r++) {
      float4 x = *(const float4*)&xs[G][r][k4 * 4];
      acc[r] += w.x * x.x + w.y * x.y + w.z * x.z + w.w * x.w;
    }
  }
  if (t == 0) {
#pragma unroll
    for (int r = 0; r < 4; r++) y0s[G][r] = acc[r];
  }
  __syncthreads();
  float escale = expf(scale[0]);
#pragma unroll
  for (int r = 0; r < 4; r++) {
    float timec = 1.f / (1.f + expf(-y0s[G][r])) * escale + 1.1f;
    float part = (t == 0) ? 0.f : acc[r] * acc[r];
    float ssum = grpReduce128(part, red);
    float s = (timec * timec - 1.f) / fmaxf(ssum, EPSF);
    float sq = sqrtf(s);
    int row = row0 + r;
    if (row < NNODE) out[row * HID + t] = (t == 0) ? timec : acc[r] * sq;
  }
}

// ---------------- CSR gather + fused centroid normalize ----------------

__global__ void k_gather(const float* __restrict__ h, const int* __restrict__ off,
                         const int* __restrict__ sperm, const float* __restrict__ wperm,
                         float* __restrict__ out) {
  __shared__ float red[2];
  int n = blockIdx.x;
  int t = threadIdx.x;
  int e0 = off[n], e1 = off[n + 1];
  float acc = 0.f;
  for (int e = e0; e < e1; ++e) {
    int s = sperm[e];
    float w = wperm[e];
    acc += w * h[(size_t)s * HID + t];
  }
  float part = (t == 0) ? acc * acc : -acc * acc;
  float d = blockReduce128(part, red);
  float denom = sqrtf(fmaxf(fabsf(d), EPSF));
  out[(size_t)n * HID + t] = acc / denom;
}

// ---------------- final segment mean + normalize ----------------

__device__ __forceinline__ int lowerBound(const int* __restrict__ a, int n, int key) {
  int lo = 0, hi = n;
  while (lo < hi) {
    int mid = (lo + hi) >> 1;
    if (a[mid] < key) lo = mid + 1; else hi = mid;
  }
  return lo;
}

__global__ void k_final(const float* __restrict__ h, const int* __restrict__ seg,
                        float* __restrict__ out) {
  __shared__ float red[2];
  int bseg = blockIdx.x;
  int t = threadIdx.x;
  int lo = lowerBound(seg, NGRAPH, bseg);
  int hi = lowerBound(seg, NGRAPH, bseg + 1);
  float acc = 0.f;
  for (int r = lo; r < hi; ++r) acc += h[(size_t)(NTREE + r) * HID + t];
  float cnt = (float)(hi - lo);
  float ave = acc / fmaxf(cnt, 1.f);
  float part = (t == 0) ? ave * ave : -ave * ave;
  float d = blockReduce128(part, red);
  float denom = sqrtf(fmaxf(fabsf(d), EPSF));
  out[bseg * HID + t] = ave / denom;
}

// ---------------- launch ----------------

extern "C" void kernel_launch(void* const* d_in, const int* in_sizes, int n_in,
                              void* d_out, int out_size, void* d_ws, size_t ws_size,
                              hipStream_t stream) {
  const float* gfeat  = (const float*)d_in[0];
  const float* tfeat  = (const float*)d_in[1];
  const float* ew     = (const float*)d_in[2];
  const float* W0     = (const float*)d_in[3];
  const float* b0     = (const float*)d_in[4];
  const float* scale0 = (const float*)d_in[5];
  const float* Wl     = (const float*)d_in[6];
  const float* bl     = (const float*)d_in[7];
  const float* scalel = (const float*)d_in[8];
  const int* esrc     = (const int*)d_in[9];
  const int* edst     = (const int*)d_in[10];
  const int* segids   = (const int*)d_in[11];
  float* outp = (float*)d_out;

  char* ws = (char*)d_ws;
  size_t o = 0;
  auto take = [&](size_t bytes) -> char* {
    char* p = ws + o;
    o = (o + bytes + 255) & ~(size_t)255;
    return p;
  };
  int*   off   = (int*)take((NNODE + 1) * sizeof(int));
  int*   cur   = (int*)take(NNODE * sizeof(int));
  int*   sperm = (int*)take(NEDGE * sizeof(int));
  float* wperm = (float*)take(NEDGE * sizeof(float));
  int*   part  = (int*)take(SCAN_BLK * sizeof(int));
  float* bufA  = (float*)take((size_t)NNODE * HID * sizeof(float));
  float* bufB  = (float*)take((size_t)NNODE * HID * sizeof(float));
  (void)ws_size; (void)in_sizes; (void)n_in; (void)out_size;

  // CSR build (by destination)
  hipMemsetAsync(cur, 0, NNODE * sizeof(int), stream);
  k_hist<<<(NEDGE + 255) / 256, 256, 0, stream>>>(edst, cur);
  k_scan1<<<NSCAN, SCAN_BLK, 0, stream>>>(cur, off, part);
  k_scan2<<<1, SCAN_BLK, 0, stream>>>(part, NSCAN);
  k_scan3<<<NSCAN, SCAN_BLK, 0, stream>>>(off, part);
  hipMemcpyAsync(cur, off, NNODE * sizeof(int), hipMemcpyDeviceToDevice, stream);
  k_fill<<<(NEDGE + 255) / 256, 256, 0, stream>>>(edst, esrc, ew, cur, sperm, wperm);

  // initial node features
  k_embed<<<NNODE, 128, 0, stream>>>(gfeat, tfeat, W0, b0, scale0, bufA);

  // 3 message-passing layers
  for (int i = 0; i < 3; i++) {
    const float* Wi = Wl + (size_t)i * HID * HID;
    const float* bi = bl + (size_t)i * HID;
    const float* si = scalel + i;
    if (i == 0)
      k_linear<0><<<(NNODE + 7) / 8, 256, 0, stream>>>(bufA, Wi, bi, si, bufB);
    else
      k_linear<1><<<(NNODE + 7) / 8, 256, 0, stream>>>(bufA, Wi, bi, si, bufB);
    k_gather<<<NNODE, 128, 0, stream>>>(bufB, off, sperm, wperm, bufA);
  }

  // segment mean + normalize
  k_final<<<NSEG, 128, 0, stream>>>(bufA, segids, outp);
}